// Round 8
// baseline (149.889 us; speedup 1.0000x reference)
//
#include <hip/hip_runtime.h>
#include <hip/hip_bf16.h>

#define H 768
#define SEQ 256
#define NPAIR 32896                // S*(S+1)/2
#define NTOT 131584                // 4*NPAIR = 514*256 exactly
#define NOUTP 160
#define OFF_H2H 263168u            // 4*32896*2
#define OFF_T2T 9737216u           // OFF_H2H + 4*24*32896*3

#define N_BPK 122880               // 24 k32-steps * 10 frags * 64 lanes * 8 bf16
#define N_FCW 1179648              // 1536*768
#define SCL 2.8853900817779268f    // 2*log2(e): pre-scale L/R so stage tanh needs no mul

typedef short bf16x8 __attribute__((ext_vector_type(8)));
typedef float f32x4 __attribute__((ext_vector_type(4)));

__device__ __forceinline__ float tanh_s(float xs) {
    // xs = 2*log2(e)*x  ->  tanh(x) = 1 - 2/(exp2(xs)+1)
    float e = __builtin_amdgcn_exp2f(xs);
    return fmaf(-2.0f, __builtin_amdgcn_rcpf(e + 1.0f), 1.0f);
}
__device__ __forceinline__ float bf_lo(int w){ return __uint_as_float(((unsigned)w) << 16); }
__device__ __forceinline__ float bf_hi(int w){ return __uint_as_float(((unsigned)w) & 0xffff0000u); }
__device__ __forceinline__ float bfu(unsigned short u){ return __uint_as_float(((unsigned)u) << 16); }
__device__ __forceinline__ int cvtpk(float lo, float hi) {
    int r;
    asm("v_cvt_pk_bf16_f32 %0, %1, %2" : "=v"(r) : "v"(lo), "v"(hi));
    return r;
}
__device__ __forceinline__ unsigned short bf16r(float x){
    unsigned int u = __float_as_uint(x);
    u += 0x7fffu + ((u >> 16) & 1u);
    return (unsigned short)(u >> 16);
}
__device__ __forceinline__ bf16x8 tanh_frag(int4 lv, int4 rv) {
    int4 st;
    st.x = cvtpk(tanh_s(bf_lo(lv.x) + bf_lo(rv.x)), tanh_s(bf_hi(lv.x) + bf_hi(rv.x)));
    st.y = cvtpk(tanh_s(bf_lo(lv.y) + bf_lo(rv.y)), tanh_s(bf_hi(lv.y) + bf_hi(rv.y)));
    st.z = cvtpk(tanh_s(bf_lo(lv.z) + bf_lo(rv.z)), tanh_s(bf_hi(lv.z) + bf_hi(rv.z)));
    st.w = cvtpk(tanh_s(bf_lo(lv.w) + bf_lo(rv.w)), tanh_s(bf_hi(lv.w) + bf_hi(rv.w)));
    return __builtin_bit_cast(bf16x8, st);
}

typedef const __attribute__((address_space(1))) unsigned int* as1_u32p;
typedef __attribute__((address_space(3))) unsigned int* as3_u32p;
__device__ __forceinline__ void gload_lds16(const void* g, void* l) {
    __builtin_amdgcn_global_load_lds((as1_u32p)g, (as3_u32p)l, 16, 0, 0);
}

__device__ __forceinline__ int row_start(int i) { return i * SEQ - (i * (i - 1)) / 2; }
__device__ __forceinline__ void pair_ij(int p, int& oi, int& oj) {
    double disc = 263169.0 - 8.0 * (double)p;   // (2S+1)^2 - 8p
    int i = (int)((513.0 - sqrt(disc)) * 0.5);
    if (i > 0 && row_start(i) > p) --i;
    while (row_start(i + 1) <= p) ++i;
    oi = i;
    oj = i + (p - row_start(i));
}
__device__ __forceinline__ int batch_of(int g) {
    return (g >= 3 * NPAIR) ? 3 : (g >= 2 * NPAIR) ? 2 : (g >= NPAIR) ? 1 : 0;
}

// ---------------- kernel 0: pack Bpk (fragment-ordered), fcwb, bc ----------------
__global__ __launch_bounds__(256) void pack_kernel(
    const float* __restrict__ h2t_w, const float* __restrict__ h2h_w,
    const float* __restrict__ t2t_w, const float* __restrict__ h2t_b,
    const float* __restrict__ h2h_b, const float* __restrict__ t2t_b,
    const float* __restrict__ fc_w,
    unsigned short* __restrict__ Bpk, unsigned short* __restrict__ fcwb,
    float* __restrict__ bc)
{
    int idx = blockIdx.x * 256 + threadIdx.x;
    if (idx < N_BPK) {
        int j = idx & 7, lane = (idx >> 3) & 63, rest = idx >> 9;
        int f = rest % 10, k32 = rest / 10;
        int n = f * 16 + (lane & 15);
        int k = k32 * 32 + ((lane >> 4) << 3) + j;
        float v = 0.f;
        if (n < 2)        v = h2t_w[n * H + k];
        else if (n < 74)  v = h2h_w[(n - 2) * H + k];
        else if (n < 146) v = t2t_w[(n - 74) * H + k];
        Bpk[idx] = bf16r(v);
    } else if (idx < N_BPK + N_FCW) {
        int q = idx - N_BPK;
        int n = q / H, k = q % H;
        float v = (n < H) ? fc_w[(size_t)n * 2 * H + k]
                          : fc_w[(size_t)(n - H) * 2 * H + H + k];
        fcwb[q] = bf16r(v);
    } else if (idx < N_BPK + N_FCW + NOUTP) {
        int q = idx - N_BPK - N_FCW;
        float v = 0.f;
        if (q < 2)        v = h2t_b[q];
        else if (q < 74)  v = h2h_b[q - 2];
        else if (q < 146) v = t2t_b[q - 74];
        bc[q] = v;
    }
}

// ---------------- kernel 1: LB/RB = hidden @ fc_w (bf16 MFMA GEMM), pre-scaled by SCL ----------------
__global__ __launch_bounds__(256, 2) void lr_mfma(
    const float* __restrict__ hidden, const unsigned short* __restrict__ fcwb,
    const float* __restrict__ fc_b,
    unsigned short* __restrict__ LB, unsigned short* __restrict__ RB)
{
    __shared__ __align__(16) char sm[24576];          // A 8KB | B 16KB
    const int tid = threadIdx.x, l = tid & 63, w = tid >> 6;
    const int wm = w >> 1, wn = w & 1;
    const int m0 = blockIdx.x * 64, n0 = blockIdx.y * 128;
    f32x4 acc[2][4] = {};
    for (int c = 0; c < 12; ++c) {
        const int k0 = c * 64;
        #pragma unroll
        for (int it = 0; it < 2; ++it) {              // A: 64 rows x 64 k, cvt f32->bf16
            int idx = tid + it * 256;
            int row = idx >> 3, k8 = idx & 7;
            const float4* src = reinterpret_cast<const float4*>(hidden + (size_t)(m0 + row) * H + k0 + k8 * 8);
            float4 a = src[0], bq = src[1];
            int4 st;
            st.x = cvtpk(a.x, a.y);  st.y = cvtpk(a.z, a.w);
            st.z = cvtpk(bq.x, bq.y); st.w = cvtpk(bq.z, bq.w);
            *reinterpret_cast<int4*>(sm + row * 128 + ((k8 * 16) ^ ((row & 7) << 4))) = st;
        }
        #pragma unroll
        for (int it = 0; it < 4; ++it) {              // B: 128 rows x 64 k
            int idx = tid + it * 256;
            int row = idx >> 3, k8 = idx & 7;
            *reinterpret_cast<int4*>(sm + 8192 + row * 128 + ((k8 * 16) ^ ((row & 7) << 4))) =
                *reinterpret_cast<const int4*>(fcwb + (size_t)(n0 + row) * H + k0 + k8 * 8);
        }
        __syncthreads();
        #pragma unroll
        for (int kk = 0; kk < 2; ++kk) {
            const int sl = kk * 4 + (l >> 4);
            const int swz = (l & 7) << 4;
            bf16x8 af[2], bfr[4];
            #pragma unroll
            for (int a = 0; a < 2; ++a) {
                int row = 32 * wm + 16 * a + (l & 15);
                af[a] = *reinterpret_cast<const bf16x8*>(sm + row * 128 + ((sl * 16) ^ swz));
            }
            #pragma unroll
            for (int f = 0; f < 4; ++f) {
                int row = 64 * wn + 16 * f + (l & 15);
                bfr[f] = *reinterpret_cast<const bf16x8*>(sm + 8192 + row * 128 + ((sl * 16) ^ swz));
            }
            #pragma unroll
            for (int a = 0; a < 2; ++a)
                #pragma unroll
                for (int f = 0; f < 4; ++f)
                    acc[a][f] = __builtin_amdgcn_mfma_f32_16x16x32_bf16(af[a], bfr[f], acc[a][f], 0, 0, 0);
        }
        __syncthreads();
    }
    #pragma unroll
    for (int a = 0; a < 2; ++a)
        #pragma unroll
        for (int f = 0; f < 4; ++f)
            #pragma unroll
            for (int r = 0; r < 4; ++r) {
                int row = m0 + 32 * wm + 16 * a + 4 * (l >> 4) + r;
                int col = n0 + 64 * wn + 16 * f + (l & 15);
                float v = acc[a][f][r];
                if (n0 < H) LB[(size_t)row * H + col] = bf16r((v + fc_b[col]) * SCL);
                else        RB[(size_t)row * H + (col - H)] = bf16r(v * SCL);
            }
}

// ---------------- kernel 2: 512-thr flat-residency pair kernel ----------------
// grid = 514 (exact), block = 8 waves, wave = 32 rows x 160 cols (acc 2x10), chunk = 64 k.
// A in regs (tanh straight into frags); B via global_load_lds dbuf, counted-vmcnt barrier.
#define SLAB_STR 166   // bf16 slab stride (83 words, odd -> conflict-free strided rows)

__global__ __launch_bounds__(512, 4) void pair_mfma(
    const unsigned short* __restrict__ LB, const unsigned short* __restrict__ RB,
    const unsigned short* __restrict__ Bpk, const float* __restrict__ bc,
    float* __restrict__ out)
{
    __shared__ __align__(16) char sm[43136];
    // pre-stage: iOf [0,1024) | jOf [1024,2048)        (aliased, consumed before staging)
    // K-loop:   B buf0 [0,20480) | buf1 [20480,40960)
    // epilogue: bf16 slab [128][166] = 42496 B at [0,42496)
    // bc_s [42496,43136) lives throughout
    int*   iOf  = reinterpret_cast<int*>(sm);
    int*   jOf  = reinterpret_cast<int*>(sm + 1024);
    float* bc_s = reinterpret_cast<float*>(sm + 42496);

    const int tid = threadIdx.x, l = tid & 63, w = tid >> 6;
    const int g0 = blockIdx.x * 256;                   // global flat pair base

    if (tid < 256) {
        int g = g0 + tid;
        int b = batch_of(g);
        int i, j; pair_ij(g - b * NPAIR, i, j);
        iOf[tid] = (b * SEQ + i) * H;
        jOf[tid] = (b * SEQ + j) * H;
    }
    if (tid < NOUTP) bc_s[tid] = bc[tid];
    __syncthreads();

    const int row0 = 32 * w + (l & 15);               // m=0 row; m=1 row = row0+16
    const int kb = (l >> 4) << 3;                     // lane k-seg base (bf16 units)
    const unsigned short* lp0 = LB + iOf[row0] + kb;
    const unsigned short* rp0 = RB + jOf[row0] + kb;
    const unsigned short* lp1 = LB + iOf[row0 + 16] + kb;
    const unsigned short* rp1 = RB + jOf[row0 + 16] + kb;
    __syncthreads();   // iOf/jOf reads done before B staging overwrites [0,2048)

    // B staging split: wave w loads groups {2w, 2w+1} (+ group 16+w for w<4)
    const char* bpk = reinterpret_cast<const char*>(Bpk);
    const int ga = 2 * w, gb = 2 * w + 1, gc = 16 + w;

    f32x4 acc[2][10] = {};

    {   // prologue: B(0) -> buf0 ; L/R(0) -> regs
        const char* bch = bpk;
        gload_lds16(bch + ga * 1024 + l * 16, sm + ga * 1024);
        gload_lds16(bch + gb * 1024 + l * 16, sm + gb * 1024);
        if (w < 4) gload_lds16(bch + gc * 1024 + l * 16, sm + gc * 1024);
        __builtin_amdgcn_sched_barrier(0);
    }
    int4 lA0 = *reinterpret_cast<const int4*>(lp0);
    int4 lA1 = *reinterpret_cast<const int4*>(lp0 + 32);
    int4 lB0 = *reinterpret_cast<const int4*>(lp1);
    int4 lB1 = *reinterpret_cast<const int4*>(lp1 + 32);
    int4 rA0 = *reinterpret_cast<const int4*>(rp0);
    int4 rA1 = *reinterpret_cast<const int4*>(rp0 + 32);
    int4 rB0 = *reinterpret_cast<const int4*>(rp1);
    int4 rB1 = *reinterpret_cast<const int4*>(rp1 + 32);
    asm volatile("s_waitcnt vmcnt(8) lgkmcnt(0)" ::: "memory");   // drain B, keep L/R in flight
    __builtin_amdgcn_s_barrier();
    __builtin_amdgcn_sched_barrier(0);

    #pragma unroll 2
    for (int c = 0; c < 11; ++c) {
        char* bufc = sm + ((c & 1) ? 20480 : 0);
        char* bufn = sm + (((c + 1) & 1) ? 20480 : 0);
        // phase 1: B(c+1) -> bufn (oldest outstanding -> drained by vmcnt(8))
        const char* bn = bpk + (c + 1) * 20480;
        gload_lds16(bn + ga * 1024 + l * 16, bufn + ga * 1024);
        gload_lds16(bn + gb * 1024 + l * 16, bufn + gb * 1024);
        if (w < 4) gload_lds16(bn + gc * 1024 + l * 16, bufn + gc * 1024);
        __builtin_amdgcn_sched_barrier(0);
        // phase 2: tanh current L/R -> A frags
        bf16x8 a00 = tanh_frag(lA0, rA0);
        bf16x8 a10 = tanh_frag(lB0, rB0);
        bf16x8 a01 = tanh_frag(lA1, rA1);
        bf16x8 a11 = tanh_frag(lB1, rB1);
        // phase 3: issue next-chunk L/R (newest outstanding: survive the barrier)
        const int co = (c + 1) * 64;
        lA0 = *reinterpret_cast<const int4*>(lp0 + co);
        lA1 = *reinterpret_cast<const int4*>(lp0 + co + 32);
        lB0 = *reinterpret_cast<const int4*>(lp1 + co);
        lB1 = *reinterpret_cast<const int4*>(lp1 + co + 32);
        rA0 = *reinterpret_cast<const int4*>(rp0 + co);
        rA1 = *reinterpret_cast<const int4*>(rp0 + co + 32);
        rB0 = *reinterpret_cast<const int4*>(rp1 + co);
        rB1 = *reinterpret_cast<const int4*>(rp1 + co + 32);
        // phase 4: MFMA on bufc
        #pragma unroll
        for (int f = 0; f < 10; ++f) {
            bf16x8 bf0 = *reinterpret_cast<const bf16x8*>(bufc + (f * 64 + l) * 16);
            acc[0][f] = __builtin_amdgcn_mfma_f32_16x16x32_bf16(a00, bf0, acc[0][f], 0, 0, 0);
            acc[1][f] = __builtin_amdgcn_mfma_f32_16x16x32_bf16(a10, bf0, acc[1][f], 0, 0, 0);
        }
        #pragma unroll
        for (int f = 0; f < 10; ++f) {
            bf16x8 bf1 = *reinterpret_cast<const bf16x8*>(bufc + ((10 + f) * 64 + l) * 16);
            acc[0][f] = __builtin_amdgcn_mfma_f32_16x16x32_bf16(a01, bf1, acc[0][f], 0, 0, 0);
            acc[1][f] = __builtin_amdgcn_mfma_f32_16x16x32_bf16(a11, bf1, acc[1][f], 0, 0, 0);
        }
        // phase 5: counted barrier — drain B(c+1), keep the 8 L/R loads in flight
        asm volatile("s_waitcnt vmcnt(8) lgkmcnt(0)" ::: "memory");
        __builtin_amdgcn_s_barrier();
        __builtin_amdgcn_sched_barrier(0);
    }
    {   // peeled chunk 11 (no prefetch)
        bf16x8 a00 = tanh_frag(lA0, rA0);
        bf16x8 a10 = tanh_frag(lB0, rB0);
        bf16x8 a01 = tanh_frag(lA1, rA1);
        bf16x8 a11 = tanh_frag(lB1, rB1);
        const char* bufc = sm + 20480;          // 11&1 = 1
        #pragma unroll
        for (int f = 0; f < 10; ++f) {
            bf16x8 bf0 = *reinterpret_cast<const bf16x8*>(bufc + (f * 64 + l) * 16);
            acc[0][f] = __builtin_amdgcn_mfma_f32_16x16x32_bf16(a00, bf0, acc[0][f], 0, 0, 0);
            acc[1][f] = __builtin_amdgcn_mfma_f32_16x16x32_bf16(a10, bf0, acc[1][f], 0, 0, 0);
        }
        #pragma unroll
        for (int f = 0; f < 10; ++f) {
            bf16x8 bf1 = *reinterpret_cast<const bf16x8*>(bufc + ((10 + f) * 64 + l) * 16);
            acc[0][f] = __builtin_amdgcn_mfma_f32_16x16x32_bf16(a01, bf1, acc[0][f], 0, 0, 0);
            acc[1][f] = __builtin_amdgcn_mfma_f32_16x16x32_bf16(a11, bf1, acc[1][f], 0, 0, 0);
        }
    }
    asm volatile("s_waitcnt lgkmcnt(0)" ::: "memory");
    __builtin_amdgcn_s_barrier();

    // epilogue: 2 halves of 128 rows; owning waves dump -> slab, all waves softmax
    unsigned short* slab = reinterpret_cast<unsigned short*>(sm);
    #pragma unroll
    for (int h = 0; h < 2; ++h) {
        if ((w >> 2) == h) {
            const int wr = 32 * (w & 3);
            #pragma unroll
            for (int m = 0; m < 2; ++m)
                #pragma unroll
                for (int f = 0; f < 10; ++f)
                    #pragma unroll
                    for (int r = 0; r < 4; ++r) {
                        int row = wr + 16 * m + 4 * (l >> 4) + r;
                        slab[row * SLAB_STR + f * 16 + (l & 15)] = bf16r(acc[m][f][r]);
                    }
        }
        __syncthreads();
        if (tid < 256) {                                 // h2t: 128 rows x 2 (out idx = 2g+tt)
            int row = tid >> 1, tt = tid & 1;
            int g = g0 + 128 * h + row;
            float val = bfu(slab[row * SLAB_STR + tt]) + bc_s[tt];
            __builtin_nontemporal_store(val, &out[(size_t)g * 2 + tt]);
        }
        #pragma unroll
        for (int it = 0; it < 12; ++it) {                // 48 rr x 128 rows
            int item = it * 512 + tid;
            int pr = item & 127, rr = item >> 7;
            int g = g0 + 128 * h + pr;
            int b = batch_of(g);
            int p = g - b * NPAIR;
            int ob = 2 + rr * 3;
            const unsigned short* sp = slab + pr * SLAB_STR + ob;
            float l0 = bfu(sp[0]) + bc_s[ob + 0];
            float l1 = bfu(sp[1]) + bc_s[ob + 1];
            float l2 = bfu(sp[2]) + bc_s[ob + 2];
            float mx = fmaxf(l0, fmaxf(l1, l2));
            float e0 = __expf(l0 - mx), e1 = __expf(l1 - mx), e2 = __expf(l2 - mx);
            float inv = __fdividef(1.0f, e0 + e1 + e2);
            size_t base = (rr < 24)
                ? (size_t)OFF_H2H + ((size_t)(b * 24 + rr) * NPAIR + p) * 3
                : (size_t)OFF_T2T + ((size_t)(b * 24 + rr - 24) * NPAIR + p) * 3;
            __builtin_nontemporal_store(e0 * inv, &out[base + 0]);
            __builtin_nontemporal_store(e1 * inv, &out[base + 1]);
            __builtin_nontemporal_store(e2 * inv, &out[base + 2]);
        }
        __syncthreads();
    }
}

extern "C" void kernel_launch(void* const* d_in, const int* in_sizes, int n_in,
                              void* d_out, int out_size, void* d_ws, size_t ws_size,
                              hipStream_t stream) {
    const float* hidden = (const float*)d_in[0];
    const float* fc_w   = (const float*)d_in[1];
    const float* fc_b   = (const float*)d_in[2];
    const float* h2t_w  = (const float*)d_in[3];
    const float* h2t_b  = (const float*)d_in[4];
    const float* h2h_w  = (const float*)d_in[5];
    const float* h2h_b  = (const float*)d_in[6];
    const float* t2t_w  = (const float*)d_in[7];
    const float* t2t_b  = (const float*)d_in[8];

    char* wsb = (char*)d_ws;
    unsigned short* LBw  = (unsigned short*)(wsb);              // 1024*768 bf16 = 1.5 MB
    unsigned short* RBw  = (unsigned short*)(wsb + 1572864);    // 1.5 MB
    unsigned short* Bpk  = (unsigned short*)(wsb + 3145728);    // 240 KB
    unsigned short* fcwb = (unsigned short*)(wsb + 3391488);    // 2.25 MB
    float*          bc   = (float*)        (wsb + 5750784);     // 640 B

    float* out = (float*)d_out;

    pack_kernel<<<(N_BPK + N_FCW + NOUTP + 255) / 256, 256, 0, stream>>>(
        h2t_w, h2h_w, t2t_w, h2t_b, h2h_b, t2t_b, fc_w, Bpk, fcwb, bc);
    lr_mfma<<<dim3(16, 12), 256, 0, stream>>>(hidden, fcwb, fc_b, LBw, RBw);
    pair_mfma<<<514, 512, 0, stream>>>(LBw, RBw, Bpk, bc, out);
}

// Round 9
// 95.749 us; speedup vs baseline: 1.5654x; 1.5654x over previous
//
#include <hip/hip_runtime.h>
#include <hip/hip_bf16.h>

#define H 768
#define SEQ 256
#define NPAIR 32896                // S*(S+1)/2 = 64*514
#define NTOT 131584                // 4*NPAIR = 2056*64
#define NOUTP 160
#define OFF_H2H 263168u            // 4*32896*2
#define OFF_T2T 9737216u           // OFF_H2H + 4*24*32896*3

#define N_BPK 122880               // 24 chunks * 10 frags * 64 lanes * 8 bf16 (real slots)
#define N_FCW 1179648              // 1536*768
#define SCL 2.8853900817779268f    // 2*log2(e): pre-scale L/R so stage tanh needs no mul

#define CH 32                      // k-elems per chunk
#define NCH 24
#define BSLOT 12288                // padded B chunk bytes (768 x 16B slots; real 10240)
#define SLAB_STR 166               // bf16 slab stride (83 words, odd -> conflict-free)

typedef short bf16x8 __attribute__((ext_vector_type(8)));
typedef float f32x4 __attribute__((ext_vector_type(4)));

__device__ __forceinline__ float tanh_s(float xs) {
    // xs = 2*log2(e)*x  ->  tanh(x) = 1 - 2/(exp2(xs)+1)
    float e = __builtin_amdgcn_exp2f(xs);
    return fmaf(-2.0f, __builtin_amdgcn_rcpf(e + 1.0f), 1.0f);
}
__device__ __forceinline__ float bf_lo(int w){ return __uint_as_float(((unsigned)w) << 16); }
__device__ __forceinline__ float bf_hi(int w){ return __uint_as_float(((unsigned)w) & 0xffff0000u); }
__device__ __forceinline__ float bfu(unsigned short u){ return __uint_as_float(((unsigned)u) << 16); }
__device__ __forceinline__ int cvtpk(float lo, float hi) {
    int r;
    asm("v_cvt_pk_bf16_f32 %0, %1, %2" : "=v"(r) : "v"(lo), "v"(hi));
    return r;
}
__device__ __forceinline__ unsigned short bf16r(float x){
    unsigned int u = __float_as_uint(x);
    u += 0x7fffu + ((u >> 16) & 1u);
    return (unsigned short)(u >> 16);
}
__device__ __forceinline__ bf16x8 tanh_frag(int4 lv, int4 rv) {
    int4 st;
    st.x = cvtpk(tanh_s(bf_lo(lv.x) + bf_lo(rv.x)), tanh_s(bf_hi(lv.x) + bf_hi(rv.x)));
    st.y = cvtpk(tanh_s(bf_lo(lv.y) + bf_lo(rv.y)), tanh_s(bf_hi(lv.y) + bf_hi(rv.y)));
    st.z = cvtpk(tanh_s(bf_lo(lv.z) + bf_lo(rv.z)), tanh_s(bf_hi(lv.z) + bf_hi(rv.z)));
    st.w = cvtpk(tanh_s(bf_lo(lv.w) + bf_lo(rv.w)), tanh_s(bf_hi(lv.w) + bf_hi(rv.w)));
    return __builtin_bit_cast(bf16x8, st);
}

typedef const __attribute__((address_space(1))) unsigned int* as1_u32p;
typedef __attribute__((address_space(3))) unsigned int* as3_u32p;
__device__ __forceinline__ void gload_lds16(const void* g, void* l) {
    __builtin_amdgcn_global_load_lds((as1_u32p)g, (as3_u32p)l, 16, 0, 0);
}

__device__ __forceinline__ int row_start(int i) { return i * SEQ - (i * (i - 1)) / 2; }
__device__ __forceinline__ void pair_ij(int p, int& oi, int& oj) {
    double disc = 263169.0 - 8.0 * (double)p;   // (2S+1)^2 - 8p
    int i = (int)((513.0 - sqrt(disc)) * 0.5);
    if (i > 0 && row_start(i) > p) --i;
    while (row_start(i + 1) <= p) ++i;
    oi = i;
    oj = i + (p - row_start(i));
}
__device__ __forceinline__ int batch_of(int g) {
    return (g >= 3 * NPAIR) ? 3 : (g >= 2 * NPAIR) ? 2 : (g >= NPAIR) ? 1 : 0;
}

// ---------------- kernel 0: pack Bpk (fragment-ordered, 12KB-strided chunks), fcwb, bc ----------------
__global__ __launch_bounds__(256) void pack_kernel(
    const float* __restrict__ h2t_w, const float* __restrict__ h2h_w,
    const float* __restrict__ t2t_w, const float* __restrict__ h2t_b,
    const float* __restrict__ h2h_b, const float* __restrict__ t2t_b,
    const float* __restrict__ fc_w,
    unsigned short* __restrict__ Bpk, unsigned short* __restrict__ fcwb,
    float* __restrict__ bc)
{
    int idx = blockIdx.x * 256 + threadIdx.x;
    if (idx < N_BPK) {
        int j = idx & 7, lane = (idx >> 3) & 63, rest = idx >> 9;
        int f = rest % 10, c = rest / 10;
        int n = f * 16 + (lane & 15);
        int k = c * CH + ((lane >> 4) << 3) + j;
        float v = 0.f;
        if (n < 2)        v = h2t_w[n * H + k];
        else if (n < 74)  v = h2h_w[(n - 2) * H + k];
        else if (n < 146) v = t2t_w[(n - 74) * H + k];
        Bpk[c * 6144 + (idx - c * 5120)] = bf16r(v);     // 6144 shorts = 12288 B stride
    } else if (idx < N_BPK + N_FCW) {
        int q = idx - N_BPK;
        int n = q / H, k = q % H;
        float v = (n < H) ? fc_w[(size_t)n * 2 * H + k]
                          : fc_w[(size_t)(n - H) * 2 * H + H + k];
        fcwb[q] = bf16r(v);
    } else if (idx < N_BPK + N_FCW + NOUTP) {
        int q = idx - N_BPK - N_FCW;
        float v = 0.f;
        if (q < 2)        v = h2t_b[q];
        else if (q < 74)  v = h2h_b[q - 2];
        else if (q < 146) v = t2t_b[q - 74];
        bc[q] = v;
    }
}

// ---------------- kernel 1: LB/RB = hidden @ fc_w (bf16 MFMA GEMM), pre-scaled by SCL ----------------
__global__ __launch_bounds__(256, 2) void lr_mfma(
    const float* __restrict__ hidden, const unsigned short* __restrict__ fcwb,
    const float* __restrict__ fc_b,
    unsigned short* __restrict__ LB, unsigned short* __restrict__ RB)
{
    __shared__ __align__(16) char sm[24576];          // A 8KB | B 16KB
    const int tid = threadIdx.x, l = tid & 63, w = tid >> 6;
    const int wm = w >> 1, wn = w & 1;
    const int m0 = blockIdx.x * 64, n0 = blockIdx.y * 128;
    f32x4 acc[2][4] = {};
    for (int c = 0; c < 12; ++c) {
        const int k0 = c * 64;
        #pragma unroll
        for (int it = 0; it < 2; ++it) {              // A: 64 rows x 64 k, cvt f32->bf16
            int idx = tid + it * 256;
            int row = idx >> 3, k8 = idx & 7;
            const float4* src = reinterpret_cast<const float4*>(hidden + (size_t)(m0 + row) * H + k0 + k8 * 8);
            float4 a = src[0], bq = src[1];
            int4 st;
            st.x = cvtpk(a.x, a.y);  st.y = cvtpk(a.z, a.w);
            st.z = cvtpk(bq.x, bq.y); st.w = cvtpk(bq.z, bq.w);
            *reinterpret_cast<int4*>(sm + row * 128 + ((k8 * 16) ^ ((row & 7) << 4))) = st;
        }
        #pragma unroll
        for (int it = 0; it < 4; ++it) {              // B: 128 rows x 64 k
            int idx = tid + it * 256;
            int row = idx >> 3, k8 = idx & 7;
            *reinterpret_cast<int4*>(sm + 8192 + row * 128 + ((k8 * 16) ^ ((row & 7) << 4))) =
                *reinterpret_cast<const int4*>(fcwb + (size_t)(n0 + row) * H + k0 + k8 * 8);
        }
        __syncthreads();
        #pragma unroll
        for (int kk = 0; kk < 2; ++kk) {
            const int sl = kk * 4 + (l >> 4);
            const int swz = (l & 7) << 4;
            bf16x8 af[2], bfr[4];
            #pragma unroll
            for (int a = 0; a < 2; ++a) {
                int row = 32 * wm + 16 * a + (l & 15);
                af[a] = *reinterpret_cast<const bf16x8*>(sm + row * 128 + ((sl * 16) ^ swz));
            }
            #pragma unroll
            for (int f = 0; f < 4; ++f) {
                int row = 64 * wn + 16 * f + (l & 15);
                bfr[f] = *reinterpret_cast<const bf16x8*>(sm + 8192 + row * 128 + ((sl * 16) ^ swz));
            }
            #pragma unroll
            for (int a = 0; a < 2; ++a)
                #pragma unroll
                for (int f = 0; f < 4; ++f)
                    acc[a][f] = __builtin_amdgcn_mfma_f32_16x16x32_bf16(af[a], bfr[f], acc[a][f], 0, 0, 0);
        }
        __syncthreads();
    }
    #pragma unroll
    for (int a = 0; a < 2; ++a)
        #pragma unroll
        for (int f = 0; f < 4; ++f)
            #pragma unroll
            for (int r = 0; r < 4; ++r) {
                int row = m0 + 32 * wm + 16 * a + 4 * (l >> 4) + r;
                int col = n0 + 64 * wn + 16 * f + (l & 15);
                float v = acc[a][f][r];
                if (n0 < H) LB[(size_t)row * H + col] = bf16r((v + fc_b[col]) * SCL);
                else        RB[(size_t)row * H + (col - H)] = bf16r(v * SCL);
            }
}

// ---------------- kernel 2: lean-wave pair kernel ----------------
// block = 256 thr (4 waves), wave = 16 rows x 160 cols (acc[10] = 40 regs), M = 64 pairs,
// chunk = 32 k (24 chunks). A: tanh straight into frags (1 frag/thread/chunk).
// B: 3 uniform global_load_lds per thread per chunk into 12KB dbuf half; counted vmcnt(2) barrier.
__global__ __launch_bounds__(256, 4) void pair_mfma(
    const unsigned short* __restrict__ LB, const unsigned short* __restrict__ RB,
    const unsigned short* __restrict__ Bpk, const float* __restrict__ bc,
    float* __restrict__ out)
{
    __shared__ __align__(16) char sm[25216];
    // pre-stage: iOf [0,256) | jOf [256,512)   (aliased into dbuf region)
    // K-loop:   B buf0 [0,12288) | buf1 [12288,24576)
    // epilogue: bf16 slab [64][166] = 21248 B at [0,21248)
    // bc_s [24576,25216) lives throughout
    int*   iOf  = reinterpret_cast<int*>(sm);
    int*   jOf  = reinterpret_cast<int*>(sm + 256);
    float* bc_s = reinterpret_cast<float*>(sm + 24576);

    const int tid = threadIdx.x, l = tid & 63, w = tid >> 6;
    const int g0 = blockIdx.x * 64;                  // block never spans a batch (NPAIR % 64 == 0)
    const int b = batch_of(g0);
    const int p0 = g0 - b * NPAIR;

    if (tid < 64) {
        int i, j; pair_ij(p0 + tid, i, j);
        iOf[tid] = (b * SEQ + i) * H;
        jOf[tid] = (b * SEQ + j) * H;
    }
    if (tid < NOUTP) bc_s[tid] = bc[tid];
    __syncthreads();

    const int row = 16 * w + (l & 15);
    const unsigned short* lp = LB + iOf[row] + ((l >> 4) << 3);
    const unsigned short* rp = RB + jOf[row] + ((l >> 4) << 3);
    __syncthreads();   // iOf/jOf consumed before B staging overwrites [0,512)

    // B: per-thread 3 uniform slots; per-lane src, wave-uniform LDS dest
    const char* bp = reinterpret_cast<const char*>(Bpk) + w * 1024 + l * 16;
    const int d0 = w * 1024;

    f32x4 acc[10] = {};

    {   // prologue: B(0) -> buf0 ; L/R(0) -> regs
        gload_lds16(bp,        sm + d0);
        gload_lds16(bp + 4096, sm + 4096 + d0);
        gload_lds16(bp + 8192, sm + 8192 + d0);
        __builtin_amdgcn_sched_barrier(0);
    }
    int4 lvC = *reinterpret_cast<const int4*>(lp);
    int4 rvC = *reinterpret_cast<const int4*>(rp);
    asm volatile("s_waitcnt vmcnt(2)" ::: "memory");   // drain B(0), keep L/R in flight
    __builtin_amdgcn_s_barrier();
    __builtin_amdgcn_sched_barrier(0);

    for (int c = 0; c < NCH - 1; ++c) {
        char* bufn = sm + (((c + 1) & 1) ? BSLOT : 0);
        const char* bn = bp + (c + 1) * BSLOT;
        // phase 1: B(c+1) -> bufn (oldest outstanding)
        gload_lds16(bn,        bufn + d0);
        gload_lds16(bn + 4096, bufn + 4096 + d0);
        gload_lds16(bn + 8192, bufn + 8192 + d0);
        __builtin_amdgcn_sched_barrier(0);
        // phase 2: tanh current L/R -> A frag (auto-vmcnt waits only the 2 L/R)
        bf16x8 a0 = tanh_frag(lvC, rvC);
        // phase 3: issue next-chunk L/R (newest: survive the barrier)
        const int co = (c + 1) * CH;
        int4 lvN = *reinterpret_cast<const int4*>(lp + co);
        int4 rvN = *reinterpret_cast<const int4*>(rp + co);
        // phase 4: 10 x {ds_read_b128 + MFMA} on bufc
        const char* bufc = sm + ((c & 1) ? BSLOT : 0);
        #pragma unroll
        for (int f = 0; f < 10; ++f) {
            bf16x8 bfr = *reinterpret_cast<const bf16x8*>(bufc + (f * 64 + l) * 16);
            acc[f] = __builtin_amdgcn_mfma_f32_16x16x32_bf16(a0, bfr, acc[f], 0, 0, 0);
        }
        // phase 5: counted barrier — drain B(c+1) (3), keep the 2 L/R in flight
        asm volatile("s_waitcnt vmcnt(2)" ::: "memory");
        __builtin_amdgcn_s_barrier();
        __builtin_amdgcn_sched_barrier(0);
        lvC = lvN; rvC = rvN;
    }
    {   // peeled chunk 23 (no prefetch); bufc = buf1 (23 odd)
        bf16x8 a0 = tanh_frag(lvC, rvC);
        const char* bufc = sm + BSLOT;
        #pragma unroll
        for (int f = 0; f < 10; ++f) {
            bf16x8 bfr = *reinterpret_cast<const bf16x8*>(bufc + (f * 64 + l) * 16);
            acc[f] = __builtin_amdgcn_mfma_f32_16x16x32_bf16(a0, bfr, acc[f], 0, 0, 0);
        }
    }
    asm volatile("s_waitcnt lgkmcnt(0)" ::: "memory");   // all LDS reads retired before slab aliases
    __builtin_amdgcn_s_barrier();

    // epilogue: all 4 waves dump 64 rows -> slab, one barrier, parallel softmax
    unsigned short* slab = reinterpret_cast<unsigned short*>(sm);
    #pragma unroll
    for (int f = 0; f < 10; ++f)
        #pragma unroll
        for (int r = 0; r < 4; ++r) {
            int rw = 16 * w + 4 * (l >> 4) + r;
            slab[rw * SLAB_STR + f * 16 + (l & 15)] = bf16r(acc[f][r]);
        }
    __syncthreads();

    if (tid < 128) {                                 // h2t: 64 rows x 2 (flat out idx = 2g+tt)
        int pr = tid >> 1, tt = tid & 1;
        float val = bfu(slab[pr * SLAB_STR + tt]) + bc_s[tt];
        __builtin_nontemporal_store(val, &out[(size_t)(g0 + pr) * 2 + tt]);
    }
    #pragma unroll
    for (int it = 0; it < 12; ++it) {                // 48 rr x 64 rows, rr-major (coalesced stores)
        int item = it * 256 + tid;
        int pr = item & 63, rr = item >> 6;
        int p = p0 + pr;
        int ob = 2 + rr * 3;
        const unsigned short* sp = slab + pr * SLAB_STR + ob;
        float l0 = bfu(sp[0]) + bc_s[ob + 0];
        float l1 = bfu(sp[1]) + bc_s[ob + 1];
        float l2 = bfu(sp[2]) + bc_s[ob + 2];
        float mx = fmaxf(l0, fmaxf(l1, l2));
        float e0 = __expf(l0 - mx), e1 = __expf(l1 - mx), e2 = __expf(l2 - mx);
        float inv = __fdividef(1.0f, e0 + e1 + e2);
        size_t base = (rr < 24)
            ? (size_t)OFF_H2H + ((size_t)(b * 24 + rr) * NPAIR + p) * 3
            : (size_t)OFF_T2T + ((size_t)(b * 24 + rr - 24) * NPAIR + p) * 3;
        __builtin_nontemporal_store(e0 * inv, &out[base + 0]);
        __builtin_nontemporal_store(e1 * inv, &out[base + 1]);
        __builtin_nontemporal_store(e2 * inv, &out[base + 2]);
    }
}

extern "C" void kernel_launch(void* const* d_in, const int* in_sizes, int n_in,
                              void* d_out, int out_size, void* d_ws, size_t ws_size,
                              hipStream_t stream) {
    const float* hidden = (const float*)d_in[0];
    const float* fc_w   = (const float*)d_in[1];
    const float* fc_b   = (const float*)d_in[2];
    const float* h2t_w  = (const float*)d_in[3];
    const float* h2t_b  = (const float*)d_in[4];
    const float* h2h_w  = (const float*)d_in[5];
    const float* h2h_b  = (const float*)d_in[6];
    const float* t2t_w  = (const float*)d_in[7];
    const float* t2t_b  = (const float*)d_in[8];

    char* wsb = (char*)d_ws;
    unsigned short* LBw  = (unsigned short*)(wsb);              // 1024*768 bf16 = 1.5 MB
    unsigned short* RBw  = (unsigned short*)(wsb + 1572864);    // 1.5 MB
    unsigned short* Bpk  = (unsigned short*)(wsb + 3145728);    // 24*12288 B = 288 KB (padded chunks)
    unsigned short* fcwb = (unsigned short*)(wsb + 3440640);    // 2.25 MB
    float*          bc   = (float*)        (wsb + 5799936);     // 640 B

    float* out = (float*)d_out;

    pack_kernel<<<(N_BPK + N_FCW + NOUTP + 255) / 256, 256, 0, stream>>>(
        h2t_w, h2h_w, t2t_w, h2t_b, h2h_b, t2t_b, fc_w, Bpk, fcwb, bc);
    lr_mfma<<<dim3(16, 12), 256, 0, stream>>>(hidden, fcwb, fc_b, LBw, RBw);
    pair_mfma<<<NTOT / 64, 256, 0, stream>>>(LBw, RBw, Bpk, bc, out);
}

// Round 10
// 93.892 us; speedup vs baseline: 1.5964x; 1.0198x over previous
//
#include <hip/hip_runtime.h>
#include <hip/hip_bf16.h>

#define H 768
#define SEQ 256
#define NPAIR 32896                // S*(S+1)/2 = 64*514
#define NTOT 131584                // 4*NPAIR = 2056*64
#define NOUTP 160
#define OFF_H2H 263168u            // 4*32896*2
#define OFF_T2T 9737216u           // OFF_H2H + 4*24*32896*3

#define N_BPK 122880               // 24 chunks * 10 frags * 64 lanes * 8 bf16 (real slots)
#define N_FCW 1179648              // 1536*768
#define SCL 2.8853900817779268f    // 2*log2(e): pre-scale L/R so stage tanh needs no mul

#define CH 32                      // k-elems per chunk
#define NCH 24
#define BSLOT 12288                // padded B chunk bytes (real 10240)
#define SLAB_STR 166               // bf16 slab stride (83 words, odd -> conflict-free)

typedef short bf16x8 __attribute__((ext_vector_type(8)));
typedef float f32x4 __attribute__((ext_vector_type(4)));

__device__ __forceinline__ float tanh_s(float xs) {
    // xs = 2*log2(e)*x  ->  tanh(x) = 1 - 2/(exp2(xs)+1)
    float e = __builtin_amdgcn_exp2f(xs);
    return fmaf(-2.0f, __builtin_amdgcn_rcpf(e + 1.0f), 1.0f);
}
__device__ __forceinline__ float bf_lo(int w){ return __uint_as_float(((unsigned)w) << 16); }
__device__ __forceinline__ float bf_hi(int w){ return __uint_as_float(((unsigned)w) & 0xffff0000u); }
__device__ __forceinline__ float bfu(unsigned short u){ return __uint_as_float(((unsigned)u) << 16); }
__device__ __forceinline__ int cvtpk(float lo, float hi) {
    int r;
    asm("v_cvt_pk_bf16_f32 %0, %1, %2" : "=v"(r) : "v"(lo), "v"(hi));
    return r;
}
__device__ __forceinline__ unsigned short bf16r(float x){
    unsigned int u = __float_as_uint(x);
    u += 0x7fffu + ((u >> 16) & 1u);
    return (unsigned short)(u >> 16);
}
__device__ __forceinline__ bf16x8 tanh_frag(int4 lv, int4 rv) {
    int4 st;
    st.x = cvtpk(tanh_s(bf_lo(lv.x) + bf_lo(rv.x)), tanh_s(bf_hi(lv.x) + bf_hi(rv.x)));
    st.y = cvtpk(tanh_s(bf_lo(lv.y) + bf_lo(rv.y)), tanh_s(bf_hi(lv.y) + bf_hi(rv.y)));
    st.z = cvtpk(tanh_s(bf_lo(lv.z) + bf_lo(rv.z)), tanh_s(bf_hi(lv.z) + bf_hi(rv.z)));
    st.w = cvtpk(tanh_s(bf_lo(lv.w) + bf_lo(rv.w)), tanh_s(bf_hi(lv.w) + bf_hi(rv.w)));
    return __builtin_bit_cast(bf16x8, st);
}

typedef const __attribute__((address_space(1))) unsigned int* as1_u32p;
typedef __attribute__((address_space(3))) unsigned int* as3_u32p;
__device__ __forceinline__ void gload_lds16(const void* g, void* l) {
    __builtin_amdgcn_global_load_lds((as1_u32p)g, (as3_u32p)l, 16, 0, 0);
}

__device__ __forceinline__ int row_start(int i) { return i * SEQ - (i * (i - 1)) / 2; }
__device__ __forceinline__ void pair_ij(int p, int& oi, int& oj) {
    double disc = 263169.0 - 8.0 * (double)p;   // (2S+1)^2 - 8p
    int i = (int)((513.0 - sqrt(disc)) * 0.5);
    if (i > 0 && row_start(i) > p) --i;
    while (row_start(i + 1) <= p) ++i;
    oi = i;
    oj = i + (p - row_start(i));
}
__device__ __forceinline__ int batch_of(int g) {
    return (g >= 3 * NPAIR) ? 3 : (g >= 2 * NPAIR) ? 2 : (g >= NPAIR) ? 1 : 0;
}

// ---------------- kernel 0: pack Bpk (fragment-ordered, 12KB-strided chunks), fcwb, bc ----------------
__global__ __launch_bounds__(256) void pack_kernel(
    const float* __restrict__ h2t_w, const float* __restrict__ h2h_w,
    const float* __restrict__ t2t_w, const float* __restrict__ h2t_b,
    const float* __restrict__ h2h_b, const float* __restrict__ t2t_b,
    const float* __restrict__ fc_w,
    unsigned short* __restrict__ Bpk, unsigned short* __restrict__ fcwb,
    float* __restrict__ bc)
{
    int idx = blockIdx.x * 256 + threadIdx.x;
    if (idx < N_BPK) {
        int j = idx & 7, lane = (idx >> 3) & 63, rest = idx >> 9;
        int f = rest % 10, c = rest / 10;
        int n = f * 16 + (lane & 15);
        int k = c * CH + ((lane >> 4) << 3) + j;
        float v = 0.f;
        if (n < 2)        v = h2t_w[n * H + k];
        else if (n < 74)  v = h2h_w[(n - 2) * H + k];
        else if (n < 146) v = t2t_w[(n - 74) * H + k];
        Bpk[c * 6144 + (idx - c * 5120)] = bf16r(v);     // 6144 shorts = 12288 B stride
    } else if (idx < N_BPK + N_FCW) {
        int q = idx - N_BPK;
        int n = q / H, k = q % H;
        float v = (n < H) ? fc_w[(size_t)n * 2 * H + k]
                          : fc_w[(size_t)(n - H) * 2 * H + H + k];
        fcwb[q] = bf16r(v);
    } else if (idx < N_BPK + N_FCW + NOUTP) {
        int q = idx - N_BPK - N_FCW;
        float v = 0.f;
        if (q < 2)        v = h2t_b[q];
        else if (q < 74)  v = h2h_b[q - 2];
        else if (q < 146) v = t2t_b[q - 74];
        bc[q] = v;
    }
}

// ---------------- kernel 1: LB/RB = hidden @ fc_w (bf16 MFMA GEMM), pre-scaled by SCL ----------------
__global__ __launch_bounds__(256, 2) void lr_mfma(
    const float* __restrict__ hidden, const unsigned short* __restrict__ fcwb,
    const float* __restrict__ fc_b,
    unsigned short* __restrict__ LB, unsigned short* __restrict__ RB)
{
    __shared__ __align__(16) char sm[24576];          // A 8KB | B 16KB
    const int tid = threadIdx.x, l = tid & 63, w = tid >> 6;
    const int wm = w >> 1, wn = w & 1;
    const int m0 = blockIdx.x * 64, n0 = blockIdx.y * 128;
    f32x4 acc[2][4] = {};
    for (int c = 0; c < 12; ++c) {
        const int k0 = c * 64;
        #pragma unroll
        for (int it = 0; it < 2; ++it) {              // A: 64 rows x 64 k, cvt f32->bf16
            int idx = tid + it * 256;
            int row = idx >> 3, k8 = idx & 7;
            const float4* src = reinterpret_cast<const float4*>(hidden + (size_t)(m0 + row) * H + k0 + k8 * 8);
            float4 a = src[0], bq = src[1];
            int4 st;
            st.x = cvtpk(a.x, a.y);  st.y = cvtpk(a.z, a.w);
            st.z = cvtpk(bq.x, bq.y); st.w = cvtpk(bq.z, bq.w);
            *reinterpret_cast<int4*>(sm + row * 128 + ((k8 * 16) ^ ((row & 7) << 4))) = st;
        }
        #pragma unroll
        for (int it = 0; it < 4; ++it) {              // B: 128 rows x 64 k
            int idx = tid + it * 256;
            int row = idx >> 3, k8 = idx & 7;
            *reinterpret_cast<int4*>(sm + 8192 + row * 128 + ((k8 * 16) ^ ((row & 7) << 4))) =
                *reinterpret_cast<const int4*>(fcwb + (size_t)(n0 + row) * H + k0 + k8 * 8);
        }
        __syncthreads();
        #pragma unroll
        for (int kk = 0; kk < 2; ++kk) {
            const int sl = kk * 4 + (l >> 4);
            const int swz = (l & 7) << 4;
            bf16x8 af[2], bfr[4];
            #pragma unroll
            for (int a = 0; a < 2; ++a) {
                int row = 32 * wm + 16 * a + (l & 15);
                af[a] = *reinterpret_cast<const bf16x8*>(sm + row * 128 + ((sl * 16) ^ swz));
            }
            #pragma unroll
            for (int f = 0; f < 4; ++f) {
                int row = 64 * wn + 16 * f + (l & 15);
                bfr[f] = *reinterpret_cast<const bf16x8*>(sm + 8192 + row * 128 + ((sl * 16) ^ swz));
            }
            #pragma unroll
            for (int a = 0; a < 2; ++a)
                #pragma unroll
                for (int f = 0; f < 4; ++f)
                    acc[a][f] = __builtin_amdgcn_mfma_f32_16x16x32_bf16(af[a], bfr[f], acc[a][f], 0, 0, 0);
        }
        __syncthreads();
    }
    #pragma unroll
    for (int a = 0; a < 2; ++a)
        #pragma unroll
        for (int f = 0; f < 4; ++f)
            #pragma unroll
            for (int r = 0; r < 4; ++r) {
                int row = m0 + 32 * wm + 16 * a + 4 * (l >> 4) + r;
                int col = n0 + 64 * wn + 16 * f + (l & 15);
                float v = acc[a][f][r];
                if (n0 < H) LB[(size_t)row * H + col] = bf16r((v + fc_b[col]) * SCL);
                else        RB[(size_t)row * H + (col - H)] = bf16r(v * SCL);
            }
}

// ---------------- kernel 2: lean-wave pair kernel, 2-chunk-deep L/R prefetch ----------------
// block = 256 thr (4 waves), wave = 16 rows x 160 cols (acc[10]), M = 64 pairs, chunk = 32 k.
// Queue per chunk: B(c+1) x3 -> tanh(c) -> LR(c+2) x2 -> MFMA x10 -> vmcnt(2)+barrier.
// The counted barrier drains B and LR(c+1); LR(c+2) stays in flight -> tanh never waits.
__global__ __launch_bounds__(256, 4) void pair_mfma(
    const unsigned short* __restrict__ LB, const unsigned short* __restrict__ RB,
    const unsigned short* __restrict__ Bpk, const float* __restrict__ bc,
    float* __restrict__ out)
{
    __shared__ __align__(16) char sm[25216];
    // pre-stage: iOf [0,256) | jOf [256,512)   (aliased into dbuf region)
    // K-loop:   B buf0 [0,12288) | buf1 [12288,24576)
    // epilogue: bf16 slab [64][166] = 21248 B at [0,21248)
    // bc_s [24576,25216) lives throughout
    int*   iOf  = reinterpret_cast<int*>(sm);
    int*   jOf  = reinterpret_cast<int*>(sm + 256);
    float* bc_s = reinterpret_cast<float*>(sm + 24576);

    const int tid = threadIdx.x, l = tid & 63, w = tid >> 6;
    const int g0 = blockIdx.x * 64;                  // block never spans a batch (NPAIR % 64 == 0)
    const int b = batch_of(g0);
    const int p0 = g0 - b * NPAIR;

    if (tid < 64) {
        int i, j; pair_ij(p0 + tid, i, j);
        iOf[tid] = (b * SEQ + i) * H;
        jOf[tid] = (b * SEQ + j) * H;
    }
    if (tid < NOUTP) bc_s[tid] = bc[tid];
    __syncthreads();

    const int row = 16 * w + (l & 15);
    const unsigned short* lp = LB + iOf[row] + ((l >> 4) << 3);
    const unsigned short* rp = RB + jOf[row] + ((l >> 4) << 3);
    __syncthreads();   // iOf/jOf consumed before B staging overwrites [0,512)

    // B: per-thread 3 uniform slots; per-lane src, wave-uniform LDS dest
    const char* bp = reinterpret_cast<const char*>(Bpk) + w * 1024 + l * 16;
    const int d0 = w * 1024;

    f32x4 acc[10] = {};
    int4 lv[3], rv[3];

    {   // prologue: B(0) -> buf0 ; LR(0), LR(1) -> regs (2-deep from the start)
        gload_lds16(bp,        sm + d0);
        gload_lds16(bp + 4096, sm + 4096 + d0);
        gload_lds16(bp + 8192, sm + 8192 + d0);
        __builtin_amdgcn_sched_barrier(0);
    }
    lv[0] = *reinterpret_cast<const int4*>(lp);
    rv[0] = *reinterpret_cast<const int4*>(rp);
    lv[1] = *reinterpret_cast<const int4*>(lp + CH);
    rv[1] = *reinterpret_cast<const int4*>(rp + CH);
    asm volatile("s_waitcnt vmcnt(4)" ::: "memory");   // drain B(0); keep LR0+LR1 in flight
    __builtin_amdgcn_s_barrier();
    __builtin_amdgcn_sched_barrier(0);

    #pragma unroll
    for (int c = 0; c < NCH - 2; ++c) {               // c = 0..21, fully unrolled (static lv idx)
        char* bufn = sm + (((c + 1) & 1) ? BSLOT : 0);
        const char* bn = bp + (c + 1) * BSLOT;
        // phase 1: B(c+1) -> bufn (oldest outstanding after prior drain)
        gload_lds16(bn,        bufn + d0);
        gload_lds16(bn + 4096, bufn + 4096 + d0);
        gload_lds16(bn + 8192, bufn + 8192 + d0);
        __builtin_amdgcn_sched_barrier(0);
        // phase 2: tanh chunk c (LR(c) drained by the PREVIOUS barrier's vmcnt(2) -> no wait)
        bf16x8 a0 = tanh_frag(lv[c % 3], rv[c % 3]);
        // phase 3: issue LR(c+2) into the freed slot (newest: survives this chunk's barrier)
        const int co = (c + 2) * CH;
        lv[(c + 2) % 3] = *reinterpret_cast<const int4*>(lp + co);
        rv[(c + 2) % 3] = *reinterpret_cast<const int4*>(rp + co);
        // phase 4: 10 x {ds_read_b128 + MFMA} on bufc
        const char* bufc = sm + ((c & 1) ? BSLOT : 0);
        #pragma unroll
        for (int f = 0; f < 10; ++f) {
            bf16x8 bfr = *reinterpret_cast<const bf16x8*>(bufc + (f * 64 + l) * 16);
            acc[f] = __builtin_amdgcn_mfma_f32_16x16x32_bf16(a0, bfr, acc[f], 0, 0, 0);
        }
        // phase 5: counted barrier — drains B(c+1) and LR(c+1); leaves LR(c+2) in flight
        asm volatile("s_waitcnt vmcnt(2)" ::: "memory");
        __builtin_amdgcn_s_barrier();
        __builtin_amdgcn_sched_barrier(0);
    }
    {   // peeled chunk 22: stage B(23); no LR issue -> must drain fully (B is newest)
        char* bufn = sm + BSLOT;                      // 23 odd
        const char* bn = bp + 23 * BSLOT;
        gload_lds16(bn,        bufn + d0);
        gload_lds16(bn + 4096, bufn + 4096 + d0);
        gload_lds16(bn + 8192, bufn + 8192 + d0);
        __builtin_amdgcn_sched_barrier(0);
        bf16x8 a0 = tanh_frag(lv[22 % 3], rv[22 % 3]);
        const char* bufc = sm;                        // 22 even
        #pragma unroll
        for (int f = 0; f < 10; ++f) {
            bf16x8 bfr = *reinterpret_cast<const bf16x8*>(bufc + (f * 64 + l) * 16);
            acc[f] = __builtin_amdgcn_mfma_f32_16x16x32_bf16(a0, bfr, acc[f], 0, 0, 0);
        }
        asm volatile("s_waitcnt vmcnt(0)" ::: "memory");
        __builtin_amdgcn_s_barrier();
        __builtin_amdgcn_sched_barrier(0);
    }
    {   // peeled chunk 23 (no stage)
        bf16x8 a0 = tanh_frag(lv[23 % 3], rv[23 % 3]);
        const char* bufc = sm + BSLOT;                // 23 odd
        #pragma unroll
        for (int f = 0; f < 10; ++f) {
            bf16x8 bfr = *reinterpret_cast<const bf16x8*>(bufc + (f * 64 + l) * 16);
            acc[f] = __builtin_amdgcn_mfma_f32_16x16x32_bf16(a0, bfr, acc[f], 0, 0, 0);
        }
    }
    asm volatile("s_waitcnt lgkmcnt(0)" ::: "memory");   // all LDS reads retired before slab aliases
    __builtin_amdgcn_s_barrier();

    // epilogue: all 4 waves dump 64 rows -> slab, one barrier, parallel softmax
    unsigned short* slab = reinterpret_cast<unsigned short*>(sm);
    #pragma unroll
    for (int f = 0; f < 10; ++f)
        #pragma unroll
        for (int r = 0; r < 4; ++r) {
            int rw = 16 * w + 4 * (l >> 4) + r;
            slab[rw * SLAB_STR + f * 16 + (l & 15)] = bf16r(acc[f][r]);
        }
    __syncthreads();

    if (tid < 128) {                                 // h2t: 64 rows x 2 (flat out idx = 2g+tt)
        int pr = tid >> 1, tt = tid & 1;
        float val = bfu(slab[pr * SLAB_STR + tt]) + bc_s[tt];
        __builtin_nontemporal_store(val, &out[(size_t)(g0 + pr) * 2 + tt]);
    }
    #pragma unroll
    for (int it = 0; it < 12; ++it) {                // 48 rr x 64 rows, rr-major (coalesced stores)
        int item = it * 256 + tid;
        int pr = item & 63, rr = item >> 6;
        int p = p0 + pr;
        int ob = 2 + rr * 3;
        const unsigned short* sp = slab + pr * SLAB_STR + ob;
        float l0 = bfu(sp[0]) + bc_s[ob + 0];
        float l1 = bfu(sp[1]) + bc_s[ob + 1];
        float l2 = bfu(sp[2]) + bc_s[ob + 2];
        float mx = fmaxf(l0, fmaxf(l1, l2));
        float e0 = __expf(l0 - mx), e1 = __expf(l1 - mx), e2 = __expf(l2 - mx);
        float inv = __fdividef(1.0f, e0 + e1 + e2);
        size_t base = (rr < 24)
            ? (size_t)OFF_H2H + ((size_t)(b * 24 + rr) * NPAIR + p) * 3
            : (size_t)OFF_T2T + ((size_t)(b * 24 + rr - 24) * NPAIR + p) * 3;
        __builtin_nontemporal_store(e0 * inv, &out[base + 0]);
        __builtin_nontemporal_store(e1 * inv, &out[base + 1]);
        __builtin_nontemporal_store(e2 * inv, &out[base + 2]);
    }
}

extern "C" void kernel_launch(void* const* d_in, const int* in_sizes, int n_in,
                              void* d_out, int out_size, void* d_ws, size_t ws_size,
                              hipStream_t stream) {
    const float* hidden = (const float*)d_in[0];
    const float* fc_w   = (const float*)d_in[1];
    const float* fc_b   = (const float*)d_in[2];
    const float* h2t_w  = (const float*)d_in[3];
    const float* h2t_b  = (const float*)d_in[4];
    const float* h2h_w  = (const float*)d_in[5];
    const float* h2h_b  = (const float*)d_in[6];
    const float* t2t_w  = (const float*)d_in[7];
    const float* t2t_b  = (const float*)d_in[8];

    char* wsb = (char*)d_ws;
    unsigned short* LBw  = (unsigned short*)(wsb);              // 1024*768 bf16 = 1.5 MB
    unsigned short* RBw  = (unsigned short*)(wsb + 1572864);    // 1.5 MB
    unsigned short* Bpk  = (unsigned short*)(wsb + 3145728);    // 24*12288 B = 288 KB (padded chunks)
    unsigned short* fcwb = (unsigned short*)(wsb + 3440640);    // 2.25 MB
    float*          bc   = (float*)        (wsb + 5799936);     // 640 B

    float* out = (float*)d_out;

    pack_kernel<<<(N_BPK + N_FCW + NOUTP + 255) / 256, 256, 0, stream>>>(
        h2t_w, h2h_w, t2t_w, h2t_b, h2h_b, t2t_b, fc_w, Bpk, fcwb, bc);
    lr_mfma<<<dim3(16, 12), 256, 0, stream>>>(hidden, fcwb, fc_b, LBw, RBw);
    pair_mfma<<<NTOT / 64, 256, 0, stream>>>(LBw, RBw, Bpk, bc, out);
}